// Round 1
// baseline (13997.244 us; speedup 1.0000x reference)
//
#include <hip/hip_runtime.h>
#include <hip/hip_bf16.h>
#include <math.h>

// ---- static problem config (mirrors reference) ----
#define DIM    128
#define NPART  4096      // B*N particles
#define MREAL  4136      // NPART + B*K
#define MP     4160      // padded to 65*64; pad rows have mass 0 -> no influence
#define NSLICE 8         // j-slices for force partials
#define NJT    130       // MP / 32 j-tiles
#define NITER  50
#define NPTS   1034      // N+K points for features (batch)
#define NPAIRS 534061.0  // 1034*1033/2

// LDS swizzle: rows of 128 floats = 32 float4 slots; slot' = slot ^ ((row>>2)&7)
// -> different rows hit different bank-quads on strided reads (<=2-way conflicts).
__device__ __forceinline__ int lds_off(int row, int slot) {
  return row * DIM + ((slot ^ ((row >> 2) & 7)) << 2);
}
__device__ __forceinline__ float dot4acc(float s, float4 a, float4 b) {
  s = fmaf(a.x, b.x, s); s = fmaf(a.y, b.y, s);
  s = fmaf(a.z, b.z, s); s = fmaf(a.w, b.w, s);
  return s;
}
__device__ __forceinline__ void fma4(float4& acc, float w, float4 p) {
  acc.x = fmaf(w, p.x, acc.x); acc.y = fmaf(w, p.y, acc.y);
  acc.z = fmaf(w, p.z, acc.z); acc.w = fmaf(w, p.w, acc.w);
}

// ---------------- init: build padded state + sq + mass ----------------
__global__ __launch_bounds__(256)
void k_init(const float* __restrict__ x, const float* __restrict__ ap,
            const float* __restrict__ am, const float* __restrict__ v0in,
            float* __restrict__ r, float* __restrict__ v,
            float* __restrict__ mass, float* __restrict__ sq)
{
  int wid = threadIdx.x >> 6, ln = threadIdx.x & 63;
  int row = blockIdx.x * 4 + wid;
  int d0 = ln, d1 = ln + 64;
  size_t base = (size_t)row * DIM;
  float r0, r1, w0, w1, m;
  if (row < NPART) {
    r0 = x[base + d0]; r1 = x[base + d1]; w0 = 0.f; w1 = 0.f; m = 0.1f;
  } else if (row < MREAL) {
    int k = (row - NPART) % 10;
    r0 = ap[k * DIM + d0]; r1 = ap[k * DIM + d1];
    w0 = v0in[k * DIM + d0]; w1 = v0in[k * DIM + d1]; m = am[k];
  } else {
    r0 = r1 = w0 = w1 = 0.f; m = 0.f;
  }
  r[base + d0] = r0; r[base + d1] = r1;
  v[base + d0] = w0; v[base + d1] = w1;
  float n2 = r0 * r0 + r1 * r1;
  for (int mk = 1; mk < 64; mk <<= 1) n2 += __shfl_xor(n2, mk);
  if (ln == 0) { sq[row] = n2; mass[row] = m; }
}

// ---------------- force: fused flash-style all-pairs gravity ----------------
// grid (65 i-tiles, 8 slices), 256 thr. Writes apart[slice][row][d] = sum_j w*r_j
// and wsump[slice][row] = sum_j w  for j in this slice's tiles.
__global__ __launch_bounds__(256)
void k_force(const float* __restrict__ r, const float* __restrict__ sq,
             const float* __restrict__ mass,
             float* __restrict__ apart, float* __restrict__ wsump)
{
  __shared__ __align__(16) float ri_s[64 * DIM];   // 32 KB
  __shared__ __align__(16) float rj_s[32 * DIM];   // 16 KB
  __shared__ __align__(16) float wT_s[32 * 68];    // w transposed [j][i], pad 68
  __shared__ float sqi_s[64];
  __shared__ float sqj_s[32];
  __shared__ float mj_s[32];

  const int tid = threadIdx.x;
  const int tx = tid & 15, ty = tid >> 4;
  const int bi0 = blockIdx.x * 64;
  const int slice = blockIdx.y;
  const int swi = ty & 7;          // (row>>2)&7 for rows ty*4+a
  const int swj = (tx >> 1) & 7;   // (row>>2)&7 for rows tx*2+b

  #pragma unroll
  for (int p = 0; p < 8; ++p) {
    int q = tid + p * 256;
    int row = q >> 5, slot = q & 31;
    float4 val = *(const float4*)&r[(size_t)(bi0 + row) * DIM + slot * 4];
    *(float4*)&ri_s[lds_off(row, slot)] = val;
  }
  if (tid < 64) sqi_s[tid] = sq[bi0 + tid];

  float4 accL[4], accH[4];
  #pragma unroll
  for (int a = 0; a < 4; ++a) {
    accL[a] = make_float4(0.f, 0.f, 0.f, 0.f);
    accH[a] = make_float4(0.f, 0.f, 0.f, 0.f);
  }
  float wsacc[4] = {0.f, 0.f, 0.f, 0.f};

  for (int jt = slice; jt < NJT; jt += NSLICE) {
    __syncthreads();   // previous PV done before overwriting rj/wT
    #pragma unroll
    for (int p = 0; p < 4; ++p) {
      int q = tid + p * 256;
      int row = q >> 5, slot = q & 31;
      float4 val = *(const float4*)&r[(size_t)(jt * 32 + row) * DIM + slot * 4];
      *(float4*)&rj_s[lds_off(row, slot)] = val;
    }
    if (tid < 32) { sqj_s[tid] = sq[jt * 32 + tid]; mj_s[tid] = mass[jt * 32 + tid]; }
    __syncthreads();

    // S = ri . rj^T  (4x2 per thread)
    float sv[4][2] = {{0.f,0.f},{0.f,0.f},{0.f,0.f},{0.f,0.f}};
    #pragma unroll 8
    for (int ks = 0; ks < 32; ++ks) {
      int oi = (ks ^ swi) << 2;
      int oj = (ks ^ swj) << 2;
      float4 av[4], bv[2];
      #pragma unroll
      for (int a = 0; a < 4; ++a) av[a] = *(const float4*)&ri_s[(ty * 4 + a) * DIM + oi];
      #pragma unroll
      for (int b = 0; b < 2; ++b) bv[b] = *(const float4*)&rj_s[(tx * 2 + b) * DIM + oj];
      #pragma unroll
      for (int a = 0; a < 4; ++a)
        #pragma unroll
        for (int b = 0; b < 2; ++b) sv[a][b] = dot4acc(sv[a][b], av[a], bv[b]);
    }

    // w = m_j * d2^-1.5 (diag masked); stash transposed for PV
    float wv[4][2];
    #pragma unroll
    for (int a = 0; a < 4; ++a)
      #pragma unroll
      for (int b = 0; b < 2; ++b) {
        int gi = bi0 + ty * 4 + a;
        int gj = jt * 32 + tx * 2 + b;
        float d2 = fmaxf(sqi_s[ty * 4 + a] + sqj_s[tx * 2 + b] - 2.f * sv[a][b], 1e-6f);
        float rin = rsqrtf(d2);
        float w = mj_s[tx * 2 + b] * rin * rin * rin;
        if (gi == gj) w = 0.f;
        wv[a][b] = w;
        wsacc[a] += w;
      }
    #pragma unroll
    for (int b = 0; b < 2; ++b) {
      float4 wq = make_float4(wv[0][b], wv[1][b], wv[2][b], wv[3][b]);
      *(float4*)&wT_s[(tx * 2 + b) * 68 + ty * 4] = wq;
    }
    __syncthreads();

    // PV: acc[i][d] += w[i][j] * rj[j][d]; thread owns d = 4tx..+3 and 4tx+64..+67
    #pragma unroll 8
    for (int jb = 0; jb < 32; ++jb) {
      float4 wq = *(const float4*)&wT_s[jb * 68 + ty * 4];
      int c = (jb >> 2) & 7;
      float4 pa = *(const float4*)&rj_s[jb * DIM + ((tx ^ c) << 2)];
      float4 pb = *(const float4*)&rj_s[jb * DIM + (((tx + 16) ^ c) << 2)];
      fma4(accL[0], wq.x, pa); fma4(accH[0], wq.x, pb);
      fma4(accL[1], wq.y, pa); fma4(accH[1], wq.y, pb);
      fma4(accL[2], wq.z, pa); fma4(accH[2], wq.z, pb);
      fma4(accL[3], wq.w, pa); fma4(accH[3], wq.w, pb);
    }
  }

  #pragma unroll
  for (int a = 0; a < 4; ++a) {
    int grow = bi0 + ty * 4 + a;
    float* dst = apart + ((size_t)slice * MP + grow) * DIM;
    *(float4*)&dst[tx * 4]      = accL[a];
    *(float4*)&dst[tx * 4 + 64] = accH[a];
    float wsv = wsacc[a];
    wsv += __shfl_xor(wsv, 1);
    wsv += __shfl_xor(wsv, 2);
    wsv += __shfl_xor(wsv, 4);
    wsv += __shfl_xor(wsv, 8);
    if (tx == 0) wsump[(size_t)slice * MP + grow] = wsv;
  }
}

// ------- rowops: integrate + boundary MLP + (optional) Hamiltonian + damp/clip -------
// one wave per row, 4 rows per block
__global__ __launch_bounds__(256)
void k_rowops(float* __restrict__ r, float* __restrict__ v, float* __restrict__ sq,
              const float* __restrict__ apart, const float* __restrict__ wsump,
              const float* __restrict__ bw1, const float* __restrict__ bb1,
              const float* __restrict__ bw2, const float* __restrict__ bb2,
              const float* __restrict__ bw3, const float* __restrict__ bb3,
              const float* __restrict__ pw1, const float* __restrict__ pb1,
              const float* __restrict__ pw2,
              const float* __restrict__ kw1, const float* __restrict__ kb1,
              const float* __restrict__ kw2,
              int do_ham)
{
  int wid = threadIdx.x >> 6, ln = threadIdx.x & 63;
  int row = blockIdx.x * 4 + wid;
  int d0 = ln, d1 = ln + 64;
  __shared__ float cbuf[4][256];
  __shared__ float hbuf[4][64];
  __shared__ float gbuf[4][256];

  size_t base = (size_t)row * DIM;
  float r0 = r[base + d0], r1 = r[base + d1];
  float v0 = v[base + d0], v1 = v[base + d1];

  float s0 = 0.f, s1 = 0.f, wsv = 0.f;
  #pragma unroll
  for (int sl = 0; sl < NSLICE; ++sl) {
    s0  += apart[((size_t)sl * MP + row) * DIM + d0];
    s1  += apart[((size_t)sl * MP + row) * DIM + d1];
    wsv += wsump[(size_t)sl * MP + row];
  }
  float a0 = 1e-3f * (s0 - wsv * r0);
  float a1 = 1e-3f * (s1 - wsv * r1);
  v0 += a0 * 0.1f; v1 += a1 * 0.1f;
  r0 += v0 * 0.1f; r1 += v1 * 0.1f;

  // boundary: c = [r, v]
  cbuf[wid][d0] = r0; cbuf[wid][d1] = r1;
  cbuf[wid][128 + d0] = v0; cbuf[wid][128 + d1] = v1;
  __syncthreads();
  {
    float h = bb1[ln], hp = 0.f;
    for (int j = 0; j < 128; ++j) {
      h  += cbuf[wid][j]       * bw1[j * 64 + ln];
      hp += cbuf[wid][128 + j] * bw1[(128 + j) * 64 + ln];
    }
    hbuf[wid][ln] = tanhf(h + hp);
  }
  __syncthreads();
  float h2;
  {
    float t = bb2[ln], tp = 0.f;
    for (int j = 0; j < 32; ++j) {
      t  += hbuf[wid][j]      * bw2[j * 64 + ln];
      tp += hbuf[wid][32 + j] * bw2[(32 + j) * 64 + ln];
    }
    h2 = tanhf(t + tp);
  }
  __syncthreads();
  hbuf[wid][ln] = h2;
  __syncthreads();
  {
    float o0 = bb3[d0], o1 = bb3[d1];
    for (int j = 0; j < 64; ++j) {
      float hj = hbuf[wid][j];
      o0 += hj * bw3[j * 128 + d0];
      o1 += hj * bw3[j * 128 + d1];
    }
    r0 += 0.1f * tanhf(o0);
    r1 += 0.1f * tanhf(o1);
  }

  if (do_ham) {
    __syncthreads();
    cbuf[wid][d0] = r0; cbuf[wid][d1] = r1;   // refresh r (v part unchanged)
    __syncthreads();
    // potential net on r: g_k = (1 - tanh^2) * pw2[k]
    #pragma unroll
    for (int kk = 0; kk < 4; ++kk) {
      int k = ln + kk * 64;
      float t = pb1[k];
      for (int d = 0; d < 128; ++d) t += cbuf[wid][d] * pw1[d * 256 + k];
      t = tanhf(t);
      gbuf[wid][k] = (1.f - t * t) * pw2[k];
    }
    __syncthreads();
    {
      float g0 = 0.f, g1 = 0.f;
      for (int k = 0; k < 256; ++k) {
        float gk = gbuf[wid][k];
        g0 += gk * pw1[d0 * 256 + k];
        g1 += gk * pw1[d1 * 256 + k];
      }
      r0 -= 0.01f * g0; r1 -= 0.01f * g1;   // r += 0.01 * (-grad pot)
    }
    __syncthreads();
    // kinetic net on v
    #pragma unroll
    for (int kk = 0; kk < 4; ++kk) {
      int k = ln + kk * 64;
      float t = kb1[k];
      for (int d = 0; d < 128; ++d) t += cbuf[wid][128 + d] * kw1[d * 256 + k];
      t = tanhf(t);
      gbuf[wid][k] = (1.f - t * t) * kw2[k];
    }
    __syncthreads();
    {
      float g0 = 0.f, g1 = 0.f;
      for (int k = 0; k < 256; ++k) {
        float gk = gbuf[wid][k];
        g0 += gk * kw1[d0 * 256 + k];
        g1 += gk * kw1[d1 * 256 + k];
      }
      v0 += 0.01f * g0; v1 += 0.01f * g1;   // v += 0.01 * grad kin
    }
  }

  v0 *= 0.95f; v1 *= 0.95f;
  float n2 = r0 * r0 + r1 * r1;
  for (int mk = 1; mk < 64; mk <<= 1) n2 += __shfl_xor(n2, mk);
  float nrm = sqrtf(n2);
  float sc = fminf(1.f, 10.f / fmaxf(nrm, 1e-12f));
  r0 *= sc; r1 *= sc;
  r[base + d0] = r0; r[base + d1] = r1;
  v[base + d0] = v0; v[base + d1] = v1;
  if (ln == 0) sq[row] = n2 * sc * sc;
}

// ---------------- feature kernels ----------------
__global__ void k_statinit(double* pd_sum, double* pd_sumsq,
                           unsigned* pd_min, unsigned* pd_max)
{
  if (threadIdx.x == 0) {
    *pd_sum = 0.0; *pd_sumsq = 0.0;
    *pd_min = 0x7f7fffffu;  // FLT_MAX bits
    *pd_max = 0u;
  }
}

// com / var / skew per (batch, 32-col chunk)
__global__ __launch_bounds__(256)
void k_com(const float* __restrict__ r, const float* __restrict__ am,
           float* __restrict__ feat)
{
  int b = blockIdx.x, ch = blockIdx.y;
  int c = threadIdx.x & 31, rg = threadIdx.x >> 5;
  int col = ch * 32 + c;
  __shared__ float red[8][33];
  float amsum = 0.f;
  for (int k = 0; k < 10; ++k) amsum += am[k];
  float tot = 1024.f + amsum;

  float s = 0.f;
  for (int p = rg; p < NPTS; p += 8) {
    int row = p < 1024 ? b * 1024 + p : NPART + b * 10 + (p - 1024);
    float m = p < 1024 ? 1.f : am[p - 1024];
    s += m * r[(size_t)row * DIM + col];
  }
  red[rg][c] = s; __syncthreads();
  for (int h = 4; h >= 1; h >>= 1) { if (rg < h) red[rg][c] += red[rg + h][c]; __syncthreads(); }
  float com = red[0][c] / tot;
  __syncthreads();

  float s2 = 0.f, s3 = 0.f;
  for (int p = rg; p < NPTS; p += 8) {
    int row = p < 1024 ? b * 1024 + p : NPART + b * 10 + (p - 1024);
    float cc = r[(size_t)row * DIM + col] - com;
    s2 += cc * cc; s3 += cc * cc * cc;
  }
  red[rg][c] = s2; __syncthreads();
  for (int h = 4; h >= 1; h >>= 1) { if (rg < h) red[rg][c] += red[rg + h][c]; __syncthreads(); }
  float var = red[0][c] / 1034.f;
  __syncthreads();
  red[rg][c] = s3; __syncthreads();
  for (int h = 4; h >= 1; h >>= 1) { if (rg < h) red[rg][c] += red[rg + h][c]; __syncthreads(); }
  float skw = red[0][c] / 1034.f;
  if (rg == 0) {
    feat[b * 384 + col]       = com;
    feat[b * 384 + 128 + col] = var;
    feat[b * 384 + 256 + col] = skw;
  }
}

// pairwise-distance stats over batch 0's 1034 points
__global__ __launch_bounds__(256)
void k_pdist(const float* __restrict__ r, const float* __restrict__ sq,
             double* pd_sum, double* pd_sumsq, unsigned* pd_min, unsigned* pd_max)
{
  int ta = blockIdx.x, tb = blockIdx.y;
  if (ta > tb) return;
  __shared__ __align__(16) float pa_s[64 * DIM];
  __shared__ __align__(16) float pb_s[64 * DIM];
  __shared__ float sqa_s[64], sqb_s[64];
  const int tid = threadIdx.x;
  const int tx = tid & 15, ty = tid >> 4;

  #pragma unroll
  for (int p = 0; p < 8; ++p) {
    int q = tid + p * 256;
    int row = q >> 5, slot = q & 31;
    int pidx = ta * 64 + row;
    float4 val = make_float4(0.f, 0.f, 0.f, 0.f);
    if (pidx < NPTS) {
      int srow = pidx < 1024 ? pidx : (NPART + pidx - 1024);
      val = *(const float4*)&r[(size_t)srow * DIM + slot * 4];
    }
    *(float4*)&pa_s[lds_off(row, slot)] = val;
    pidx = tb * 64 + row;
    val = make_float4(0.f, 0.f, 0.f, 0.f);
    if (pidx < NPTS) {
      int srow = pidx < 1024 ? pidx : (NPART + pidx - 1024);
      val = *(const float4*)&r[(size_t)srow * DIM + slot * 4];
    }
    *(float4*)&pb_s[lds_off(row, slot)] = val;
  }
  if (tid < 64) {
    int pidx = ta * 64 + tid;
    sqa_s[tid] = pidx < NPTS ? sq[pidx < 1024 ? pidx : NPART + pidx - 1024] : 0.f;
  } else if (tid < 128) {
    int t2 = tid - 64;
    int pidx = tb * 64 + t2;
    sqb_s[t2] = pidx < NPTS ? sq[pidx < 1024 ? pidx : NPART + pidx - 1024] : 0.f;
  }
  __syncthreads();

  const int swi = ty & 7, swj = tx & 7;
  float sv[4][4] = {};
  #pragma unroll 8
  for (int ks = 0; ks < 32; ++ks) {
    int oi = (ks ^ swi) << 2, oj = (ks ^ swj) << 2;
    float4 av[4], bv[4];
    #pragma unroll
    for (int a = 0; a < 4; ++a) av[a] = *(const float4*)&pa_s[(ty * 4 + a) * DIM + oi];
    #pragma unroll
    for (int b = 0; b < 4; ++b) bv[b] = *(const float4*)&pb_s[(tx * 4 + b) * DIM + oj];
    #pragma unroll
    for (int a = 0; a < 4; ++a)
      #pragma unroll
      for (int b = 0; b < 4; ++b) sv[a][b] = dot4acc(sv[a][b], av[a], bv[b]);
  }

  double tsum = 0.0, tsq = 0.0;
  float tmn = 3.402823466e38f, tmx = 0.f;
  #pragma unroll
  for (int a = 0; a < 4; ++a)
    #pragma unroll
    for (int b = 0; b < 4; ++b) {
      int ga = ta * 64 + ty * 4 + a;
      int gb = tb * 64 + tx * 4 + b;
      float d2 = sqa_s[ty * 4 + a] + sqb_s[tx * 4 + b] - 2.f * sv[a][b];
      float dist = sqrtf(fmaxf(d2, 0.f));
      bool ok = (ga < NPTS) && (gb < NPTS) && ((ta != tb) || (ga < gb));
      if (ok) {
        tsum += (double)dist;
        tsq  += (double)dist * (double)dist;
        tmn = fminf(tmn, dist);
        tmx = fmaxf(tmx, dist);
      }
    }
  for (int mk = 1; mk < 64; mk <<= 1) {
    tsum += __shfl_xor(tsum, mk);
    tsq  += __shfl_xor(tsq, mk);
    tmn = fminf(tmn, __shfl_xor(tmn, mk));
    tmx = fmaxf(tmx, __shfl_xor(tmx, mk));
  }
  if ((tid & 63) == 0) {
    atomicAdd(pd_sum, tsum);
    atomicAdd(pd_sumsq, tsq);
    atomicMin(pd_min, __float_as_uint(tmn));
    atomicMax(pd_max, __float_as_uint(tmx));
  }
}

// final projection: out[b][d] = feat[b] . fw[:,d] + fb[d]
__global__ void k_proj(const float* __restrict__ feat,
                       const double* pd_sum, const double* pd_sumsq,
                       const unsigned* pd_min, const unsigned* pd_max,
                       const float* __restrict__ fw, const float* __restrict__ fb,
                       float* __restrict__ out)
{
  int t = threadIdx.x;            // 0..511
  int b = t >> 7, d = t & 127;
  double sm = *pd_sum, s2 = *pd_sumsq;
  double mean = sm / NPAIRS;
  double var = (s2 - sm * sm / NPAIRS) / (NPAIRS - 1.0);
  float sd = (float)sqrt(var > 0.0 ? var : 0.0);
  float mn = __uint_as_float(*pd_min);
  float mx = __uint_as_float(*pd_max);
  float acc = fb[d];
  for (int f = 0; f < 384; ++f) acc = fmaf(feat[b * 384 + f], fw[f * 128 + d], acc);
  acc = fmaf((float)mean, fw[384 * 128 + d], acc);
  acc = fmaf(sd,          fw[385 * 128 + d], acc);
  acc = fmaf(mn,          fw[386 * 128 + d], acc);
  acc = fmaf(mx,          fw[387 * 128 + d], acc);
  out[b * 128 + d] = acc;
}

extern "C" void kernel_launch(void* const* d_in, const int* in_sizes, int n_in,
                              void* d_out, int out_size, void* d_ws, size_t ws_size,
                              hipStream_t stream) {
  (void)in_sizes; (void)n_in; (void)out_size; (void)ws_size;
  const float* x   = (const float*)d_in[0];
  const float* ap  = (const float*)d_in[1];
  const float* am  = (const float*)d_in[2];
  const float* v0  = (const float*)d_in[3];
  const float* pw1 = (const float*)d_in[4];
  const float* pb1 = (const float*)d_in[5];
  const float* pw2 = (const float*)d_in[6];
  const float* kw1 = (const float*)d_in[8];
  const float* kb1 = (const float*)d_in[9];
  const float* kw2 = (const float*)d_in[10];
  const float* bw1 = (const float*)d_in[12];
  const float* bb1 = (const float*)d_in[13];
  const float* bw2 = (const float*)d_in[14];
  const float* bb2 = (const float*)d_in[15];
  const float* bw3 = (const float*)d_in[16];
  const float* bb3 = (const float*)d_in[17];
  const float* fw  = (const float*)d_in[18];
  const float* fb  = (const float*)d_in[19];

  // workspace layout (bytes), all 16B-aligned
  char* ws = (char*)d_ws;
  double*   pd_sum   = (double*)(ws + 0);
  double*   pd_sumsq = (double*)(ws + 8);
  unsigned* pd_min   = (unsigned*)(ws + 16);
  unsigned* pd_max   = (unsigned*)(ws + 20);
  float*    feat     = (float*)(ws + 32);                         // 4*384
  float*    r        = (float*)(ws + 6176);                       // MP*128
  float*    v        = (float*)(ws + 2136096);                    // MP*128
  float*    sq       = (float*)(ws + 4266016);                    // MP
  float*    mass     = (float*)(ws + 4282656);                    // MP
  float*    wsump    = (float*)(ws + 4299296);                    // NSLICE*MP
  float*    apart    = (float*)(ws + 4432416);                    // NSLICE*MP*128
  // total ~20.5 MB

  k_init<<<MP / 4, 256, 0, stream>>>(x, ap, am, v0, r, v, mass, sq);
  for (int it = 0; it < NITER; ++it) {
    k_force<<<dim3(MP / 64, NSLICE), 256, 0, stream>>>(r, sq, mass, apart, wsump);
    k_rowops<<<MP / 4, 256, 0, stream>>>(r, v, sq, apart, wsump,
        bw1, bb1, bw2, bb2, bw3, bb3, pw1, pb1, pw2, kw1, kb1, kw2,
        (it % 5) == 0 ? 1 : 0);
  }
  k_statinit<<<1, 64, 0, stream>>>(pd_sum, pd_sumsq, pd_min, pd_max);
  k_com<<<dim3(4, 4), 256, 0, stream>>>(r, am, feat);
  k_pdist<<<dim3(17, 17), 256, 0, stream>>>(r, sq, pd_sum, pd_sumsq, pd_min, pd_max);
  k_proj<<<1, 512, 0, stream>>>(feat, pd_sum, pd_sumsq, pd_min, pd_max, fw, fb,
                                (float*)d_out);
}

// Round 2
// 8613.651 us; speedup vs baseline: 1.6250x; 1.6250x over previous
//
#include <hip/hip_runtime.h>
#include <hip/hip_bf16.h>
#include <math.h>

// ---- static problem config ----
#define DIM    128
#define NPART  4096      // B*N particles
#define MREAL  4136      // NPART + B*K
#define MP     4224      // padded to 33*128; pad rows mass 0, r=0, never updated
#define IB     128       // i-tile per force block
#define NIB    33        // MP/IB
#define JTILE  32        // j-tile
#define NJT    132       // MP/JTILE
#define NSLICE 8
#define NROW   4136      // rows stored in apart/wsump (real rows only)
#define NITER  50
#define NPTS   1034
#define NPAIRS 534061.0

typedef __bf16 bf16x8 __attribute__((ext_vector_type(8)));
typedef float  f32x4  __attribute__((ext_vector_type(4)));

__device__ __forceinline__ f32x4 mfma16(bf16x8 a, bf16x8 b, f32x4 c) {
  return __builtin_amdgcn_mfma_f32_16x16x32_bf16(a, b, c, 0, 0, 0);
}
__device__ __forceinline__ float dot4acc(float s, float4 a, float4 b) {
  s = fmaf(a.x, b.x, s); s = fmaf(a.y, b.y, s);
  s = fmaf(a.z, b.z, s); s = fmaf(a.w, b.w, s);
  return s;
}

// LDS swizzle for k_pdist (unchanged from round 0)
__device__ __forceinline__ int lds_off(int row, int slot) {
  return row * DIM + ((slot ^ ((row >> 2) & 7)) << 2);
}

// ---------------- init: build padded state + sq ----------------
__global__ __launch_bounds__(256)
void k_init(const float* __restrict__ x, const float* __restrict__ ap,
            const float* __restrict__ am, const float* __restrict__ v0in,
            float* __restrict__ r, float* __restrict__ v, float* __restrict__ sq)
{
  int wid = threadIdx.x >> 6, ln = threadIdx.x & 63;
  int row = blockIdx.x * 4 + wid;
  int d0 = ln, d1 = ln + 64;
  size_t base = (size_t)row * DIM;
  float r0, r1, w0, w1;
  if (row < NPART) {
    r0 = x[base + d0]; r1 = x[base + d1]; w0 = 0.f; w1 = 0.f;
  } else if (row < MREAL) {
    int k = (row - NPART) % 10;
    r0 = ap[k * DIM + d0]; r1 = ap[k * DIM + d1];
    w0 = v0in[k * DIM + d0]; w1 = v0in[k * DIM + d1];
  } else {
    r0 = r1 = w0 = w1 = 0.f;
  }
  r[base + d0] = r0; r[base + d1] = r1;
  v[base + d0] = w0; v[base + d1] = w1;
  float n2 = r0 * r0 + r1 * r1;
  for (int mk = 1; mk < 64; mk <<= 1) n2 += __shfl_xor(n2, mk);
  if (ln == 0) sq[row] = n2;
}

// ---------------- force: split-bf16 MFMA all-pairs gravity ----------------
// grid (33 i-tiles, 8 slices), 256 thr = 4 waves, wave owns 32 i-rows.
// S[i][j] = ri.rj via 6-product 3-term bf16 split (f32-accurate);
// A[i][d] = w@rj via 4-product 2-term split (abs error << f32 noise).
__global__ __launch_bounds__(256, 2)
void k_force(const float* __restrict__ r, const float* __restrict__ sq,
             const float* __restrict__ am,
             float* __restrict__ apart, float* __restrict__ wsump)
{
  __shared__ __align__(16) __bf16 rjRM[3][JTILE][DIM];  // 24 KB row-major splits
  __shared__ __align__(16) __bf16 rjT[2][DIM][JTILE];   // 16 KB transposed h,m
  __shared__ __align__(16) __bf16 wsp[2][IB][JTILE];    // 16 KB w splits h,m
  __shared__ float sqj_s[JTILE], mj_s[JTILE], sqi_s[IB];

  const int tid = threadIdx.x;
  const int wv = tid >> 6, lane = tid & 63;
  const int lq = lane >> 4, lr = lane & 15;
  const int bi0 = blockIdx.x * IB;
  const int slice = blockIdx.y;

  if (tid < IB) sqi_s[tid] = sq[bi0 + tid];

  // ri A-fragments in registers, 3-way split. Lane l: row (l&15), k = kc*32+lq*8+e
  bf16x8 riH[2][4], riM[2][4], riL[2][4];
  #pragma unroll
  for (int mt = 0; mt < 2; ++mt) {
    int gi = bi0 + wv * 32 + mt * 16 + lr;
    const float* rp = &r[(size_t)gi * DIM];
    #pragma unroll
    for (int kc = 0; kc < 4; ++kc) {
      int k0 = kc * 32 + lq * 8;
      float4 f0 = *(const float4*)&rp[k0];
      float4 f1 = *(const float4*)&rp[k0 + 4];
      float xs[8] = {f0.x, f0.y, f0.z, f0.w, f1.x, f1.y, f1.z, f1.w};
      bf16x8 h, m, l;
      #pragma unroll
      for (int e = 0; e < 8; ++e) {
        float xv = xs[e];
        __bf16 hh = (__bf16)xv; float rm = xv - (float)hh;
        __bf16 mm = (__bf16)rm; rm -= (float)mm;
        __bf16 ll = (__bf16)rm;
        h[e] = hh; m[e] = mm; l[e] = ll;
      }
      riH[mt][kc] = h; riM[mt][kc] = m; riL[mt][kc] = l;
    }
  }

  f32x4 accPV[2][8];
  #pragma unroll
  for (int mt = 0; mt < 2; ++mt)
    #pragma unroll
    for (int nt = 0; nt < 8; ++nt) {
      f32x4 z = {0.f, 0.f, 0.f, 0.f};
      accPV[mt][nt] = z;
    }
  float wsacc[2][4] = {};

  for (int jt = slice; jt < NJT; jt += NSLICE) {
    __syncthreads();   // prior tile's LDS reads done

    // ---- phase A: cooperative split of rj tile (32 rows x 128) ----
    {
      int jrow = tid >> 3, cg = tid & 7;
      const float* rp = &r[(size_t)(jt * JTILE + jrow) * DIM + cg * 16];
      float4 f0 = *(const float4*)&rp[0];
      float4 f1 = *(const float4*)&rp[4];
      float4 f2 = *(const float4*)&rp[8];
      float4 f3 = *(const float4*)&rp[12];
      float xs[16] = {f0.x,f0.y,f0.z,f0.w, f1.x,f1.y,f1.z,f1.w,
                      f2.x,f2.y,f2.z,f2.w, f3.x,f3.y,f3.z,f3.w};
      __bf16 hv[16], mv[16], lv[16];
      #pragma unroll
      for (int e = 0; e < 16; ++e) {
        float xv = xs[e];
        __bf16 hh = (__bf16)xv; float rm = xv - (float)hh;
        __bf16 mm = (__bf16)rm; rm -= (float)mm;
        hv[e] = hh; mv[e] = mm; lv[e] = (__bf16)rm;
      }
      bf16x8 h0, h1, m0, m1, l0, l1;
      #pragma unroll
      for (int e = 0; e < 8; ++e) {
        h0[e] = hv[e]; h1[e] = hv[8 + e];
        m0[e] = mv[e]; m1[e] = mv[8 + e];
        l0[e] = lv[e]; l1[e] = lv[8 + e];
      }
      int c0 = (2 * cg) ^ (jrow & 7), c1 = (2 * cg + 1) ^ (jrow & 7);
      *(bf16x8*)&rjRM[0][jrow][c0 * 8] = h0; *(bf16x8*)&rjRM[0][jrow][c1 * 8] = h1;
      *(bf16x8*)&rjRM[1][jrow][c0 * 8] = m0; *(bf16x8*)&rjRM[1][jrow][c1 * 8] = m1;
      *(bf16x8*)&rjRM[2][jrow][c0 * 8] = l0; *(bf16x8*)&rjRM[2][jrow][c1 * 8] = l1;
      #pragma unroll
      for (int e = 0; e < 16; ++e) {
        int d = cg * 16 + e;
        int idx = (((jrow >> 3) ^ (d & 3)) << 3) + (jrow & 7);
        rjT[0][d][idx] = hv[e];
        rjT[1][d][idx] = mv[e];
      }
      if (tid < JTILE) {
        int gj = jt * JTILE + tid;
        sqj_s[tid] = sq[gj];
        float mm2;
        if (gj < NPART) mm2 = 0.1f;
        else if (gj < MREAL) mm2 = am[(gj - NPART) % 10];
        else mm2 = 0.f;
        mj_s[tid] = mm2;
      }
    }
    __syncthreads();

    // ---- S phase: 6-product split GEMM (B^T form) ----
    f32x4 accS[2][2];
    #pragma unroll
    for (int mt = 0; mt < 2; ++mt)
      #pragma unroll
      for (int nt = 0; nt < 2; ++nt) {
        f32x4 z = {0.f, 0.f, 0.f, 0.f};
        accS[mt][nt] = z;
      }
    #pragma unroll
    for (int kc = 0; kc < 4; ++kc) {
      bf16x8 bh[2], bm[2], bl[2];
      #pragma unroll
      for (int nt = 0; nt < 2; ++nt) {
        int j = nt * 16 + lr;
        int cc = (kc * 4 + lq) ^ (j & 7);
        bh[nt] = *(const bf16x8*)&rjRM[0][j][cc * 8];
        bm[nt] = *(const bf16x8*)&rjRM[1][j][cc * 8];
        bl[nt] = *(const bf16x8*)&rjRM[2][j][cc * 8];
      }
      #pragma unroll
      for (int mt = 0; mt < 2; ++mt)
        #pragma unroll
        for (int nt = 0; nt < 2; ++nt) {
          f32x4 c = accS[mt][nt];
          c = mfma16(riH[mt][kc], bh[nt], c);
          c = mfma16(riH[mt][kc], bm[nt], c);
          c = mfma16(riM[mt][kc], bh[nt], c);
          c = mfma16(riM[mt][kc], bm[nt], c);
          c = mfma16(riH[mt][kc], bl[nt], c);
          c = mfma16(riL[mt][kc], bh[nt], c);
          accS[mt][nt] = c;
        }
    }

    // ---- w phase: d2 -> w, accumulate wsum, 2-split w -> LDS ----
    #pragma unroll
    for (int mt = 0; mt < 2; ++mt)
      #pragma unroll
      for (int nt = 0; nt < 2; ++nt)
        #pragma unroll
        for (int rr = 0; rr < 4; ++rr) {
          int il = wv * 32 + mt * 16 + 4 * lq + rr;
          int gi = bi0 + il;
          int jl = nt * 16 + lr;
          int gj = jt * JTILE + jl;
          float d2 = sqi_s[il] + sqj_s[jl] - 2.f * accS[mt][nt][rr];
          d2 = fmaxf(d2, 1e-6f);
          float rin = rsqrtf(d2);
          float wgt = mj_s[jl] * rin * rin * rin;
          if (gi == gj) wgt = 0.f;
          wsacc[mt][rr] += wgt;
          __bf16 wh = (__bf16)wgt;
          float wr = wgt - (float)wh;
          int idx = ((((jl >> 3) ^ (il & 3))) << 3) + (lr & 7);
          wsp[0][il][idx] = wh;
          wsp[1][il][idx] = (__bf16)wr;
        }

    // ---- PV phase: A[i][d] += w @ rj (4-product split; same-wave wsp rows) ----
    bf16x8 aH[2], aM[2];
    #pragma unroll
    for (int mt = 0; mt < 2; ++mt) {
      int il = wv * 32 + mt * 16 + lr;
      int cc = lq ^ (il & 3);
      aH[mt] = *(const bf16x8*)&wsp[0][il][cc * 8];
      aM[mt] = *(const bf16x8*)&wsp[1][il][cc * 8];
    }
    #pragma unroll
    for (int nt = 0; nt < 8; ++nt) {
      int d = nt * 16 + lr;
      int cc = lq ^ (d & 3);
      bf16x8 bh = *(const bf16x8*)&rjT[0][d][cc * 8];
      bf16x8 bm = *(const bf16x8*)&rjT[1][d][cc * 8];
      #pragma unroll
      for (int mt = 0; mt < 2; ++mt) {
        f32x4 c = accPV[mt][nt];
        c = mfma16(aH[mt], bh, c);
        c = mfma16(aH[mt], bm, c);
        c = mfma16(aM[mt], bh, c);
        c = mfma16(aM[mt], bm, c);
        accPV[mt][nt] = c;
      }
    }
  }

  // ---- epilogue: wsum reduce + partial stores ----
  #pragma unroll
  for (int mt = 0; mt < 2; ++mt) {
    #pragma unroll
    for (int rr = 0; rr < 4; ++rr) {
      float val = wsacc[mt][rr];
      val += __shfl_xor(val, 1); val += __shfl_xor(val, 2);
      val += __shfl_xor(val, 4); val += __shfl_xor(val, 8);
      int gi = bi0 + wv * 32 + mt * 16 + 4 * lq + rr;
      if (lr == 0 && gi < NROW) wsump[(size_t)slice * NROW + gi] = val;
    }
    #pragma unroll
    for (int nt = 0; nt < 8; ++nt)
      #pragma unroll
      for (int rr = 0; rr < 4; ++rr) {
        int gi = bi0 + wv * 32 + mt * 16 + 4 * lq + rr;
        int d = nt * 16 + lr;
        if (gi < NROW) apart[((size_t)slice * NROW + gi) * DIM + d] = accPV[mt][nt][rr];
      }
  }
}

// ------- rowops: integrate + boundary MLP + (optional) Hamiltonian + damp/clip -------
__global__ __launch_bounds__(256)
void k_rowops(float* __restrict__ r, float* __restrict__ v, float* __restrict__ sq,
              const float* __restrict__ apart, const float* __restrict__ wsump,
              const float* __restrict__ bw1, const float* __restrict__ bb1,
              const float* __restrict__ bw2, const float* __restrict__ bb2,
              const float* __restrict__ bw3, const float* __restrict__ bb3,
              const float* __restrict__ pw1, const float* __restrict__ pb1,
              const float* __restrict__ pw2,
              const float* __restrict__ kw1, const float* __restrict__ kb1,
              const float* __restrict__ kw2,
              int do_ham)
{
  int wid = threadIdx.x >> 6, ln = threadIdx.x & 63;
  int row = blockIdx.x * 4 + wid;
  int d0 = ln, d1 = ln + 64;
  __shared__ __align__(16) float cbuf[4][256];
  __shared__ float hbuf[4][64];
  __shared__ __align__(16) float gbuf[4][256];

  size_t base = (size_t)row * DIM;
  float r0 = r[base + d0], r1 = r[base + d1];
  float v0 = v[base + d0], v1 = v[base + d1];

  float s0 = 0.f, s1 = 0.f, wsv = 0.f;
  #pragma unroll
  for (int sl = 0; sl < NSLICE; ++sl) {
    s0  += apart[((size_t)sl * NROW + row) * DIM + d0];
    s1  += apart[((size_t)sl * NROW + row) * DIM + d1];
    wsv += wsump[(size_t)sl * NROW + row];
  }
  float a0 = 1e-3f * (s0 - wsv * r0);
  float a1 = 1e-3f * (s1 - wsv * r1);
  v0 += a0 * 0.1f; v1 += a1 * 0.1f;
  r0 += v0 * 0.1f; r1 += v1 * 0.1f;

  cbuf[wid][d0] = r0; cbuf[wid][d1] = r1;
  cbuf[wid][128 + d0] = v0; cbuf[wid][128 + d1] = v1;
  __syncthreads();
  {
    float h = bb1[ln], hp = 0.f;
    for (int j = 0; j < 128; ++j) {
      h  += cbuf[wid][j]       * bw1[j * 64 + ln];
      hp += cbuf[wid][128 + j] * bw1[(128 + j) * 64 + ln];
    }
    hbuf[wid][ln] = tanhf(h + hp);
  }
  __syncthreads();
  float h2;
  {
    float t = bb2[ln], tp = 0.f;
    for (int j = 0; j < 32; ++j) {
      t  += hbuf[wid][j]      * bw2[j * 64 + ln];
      tp += hbuf[wid][32 + j] * bw2[(32 + j) * 64 + ln];
    }
    h2 = tanhf(t + tp);
  }
  __syncthreads();
  hbuf[wid][ln] = h2;
  __syncthreads();
  {
    float o0 = bb3[d0], o1 = bb3[d1];
    for (int j = 0; j < 64; ++j) {
      float hj = hbuf[wid][j];
      o0 += hj * bw3[j * 128 + d0];
      o1 += hj * bw3[j * 128 + d1];
    }
    r0 += 0.1f * tanhf(o0);
    r1 += 0.1f * tanhf(o1);
  }

  if (do_ham) {
    __syncthreads();
    cbuf[wid][d0] = r0; cbuf[wid][d1] = r1;
    __syncthreads();
    #pragma unroll
    for (int kk = 0; kk < 4; ++kk) {
      int k = ln + kk * 64;
      float t = pb1[k];
      for (int d = 0; d < 128; ++d) t += cbuf[wid][d] * pw1[d * 256 + k];
      t = tanhf(t);
      gbuf[wid][k] = (1.f - t * t) * pw2[k];
    }
    __syncthreads();
    {
      const float4* pw1v = (const float4*)pw1;
      float g0 = 0.f, g1 = 0.f;
      for (int k4 = 0; k4 < 64; ++k4) {
        float4 gk = *(const float4*)&gbuf[wid][k4 * 4];
        g0 = dot4acc(g0, gk, pw1v[d0 * 64 + k4]);
        g1 = dot4acc(g1, gk, pw1v[d1 * 64 + k4]);
      }
      r0 -= 0.01f * g0; r1 -= 0.01f * g1;
    }
    __syncthreads();
    #pragma unroll
    for (int kk = 0; kk < 4; ++kk) {
      int k = ln + kk * 64;
      float t = kb1[k];
      for (int d = 0; d < 128; ++d) t += cbuf[wid][128 + d] * kw1[d * 256 + k];
      t = tanhf(t);
      gbuf[wid][k] = (1.f - t * t) * kw2[k];
    }
    __syncthreads();
    {
      const float4* kw1v = (const float4*)kw1;
      float g0 = 0.f, g1 = 0.f;
      for (int k4 = 0; k4 < 64; ++k4) {
        float4 gk = *(const float4*)&gbuf[wid][k4 * 4];
        g0 = dot4acc(g0, gk, kw1v[d0 * 64 + k4]);
        g1 = dot4acc(g1, gk, kw1v[d1 * 64 + k4]);
      }
      v0 += 0.01f * g0; v1 += 0.01f * g1;
    }
  }

  v0 *= 0.95f; v1 *= 0.95f;
  float n2 = r0 * r0 + r1 * r1;
  for (int mk = 1; mk < 64; mk <<= 1) n2 += __shfl_xor(n2, mk);
  float nrm = sqrtf(n2);
  float sc = fminf(1.f, 10.f / fmaxf(nrm, 1e-12f));
  r0 *= sc; r1 *= sc;
  r[base + d0] = r0; r[base + d1] = r1;
  v[base + d0] = v0; v[base + d1] = v1;
  if (ln == 0) sq[row] = n2 * sc * sc;
}

// ---------------- feature kernels (unchanged) ----------------
__global__ void k_statinit(double* pd_sum, double* pd_sumsq,
                           unsigned* pd_min, unsigned* pd_max)
{
  if (threadIdx.x == 0) {
    *pd_sum = 0.0; *pd_sumsq = 0.0;
    *pd_min = 0x7f7fffffu;
    *pd_max = 0u;
  }
}

__global__ __launch_bounds__(256)
void k_com(const float* __restrict__ r, const float* __restrict__ am,
           float* __restrict__ feat)
{
  int b = blockIdx.x, ch = blockIdx.y;
  int c = threadIdx.x & 31, rg = threadIdx.x >> 5;
  int col = ch * 32 + c;
  __shared__ float red[8][33];
  float amsum = 0.f;
  for (int k = 0; k < 10; ++k) amsum += am[k];
  float tot = 1024.f + amsum;

  float s = 0.f;
  for (int p = rg; p < NPTS; p += 8) {
    int row = p < 1024 ? b * 1024 + p : NPART + b * 10 + (p - 1024);
    float m = p < 1024 ? 1.f : am[p - 1024];
    s += m * r[(size_t)row * DIM + col];
  }
  red[rg][c] = s; __syncthreads();
  for (int h = 4; h >= 1; h >>= 1) { if (rg < h) red[rg][c] += red[rg + h][c]; __syncthreads(); }
  float com = red[0][c] / tot;
  __syncthreads();

  float s2 = 0.f, s3 = 0.f;
  for (int p = rg; p < NPTS; p += 8) {
    int row = p < 1024 ? b * 1024 + p : NPART + b * 10 + (p - 1024);
    float cc = r[(size_t)row * DIM + col] - com;
    s2 += cc * cc; s3 += cc * cc * cc;
  }
  red[rg][c] = s2; __syncthreads();
  for (int h = 4; h >= 1; h >>= 1) { if (rg < h) red[rg][c] += red[rg + h][c]; __syncthreads(); }
  float var = red[0][c] / 1034.f;
  __syncthreads();
  red[rg][c] = s3; __syncthreads();
  for (int h = 4; h >= 1; h >>= 1) { if (rg < h) red[rg][c] += red[rg + h][c]; __syncthreads(); }
  float skw = red[0][c] / 1034.f;
  if (rg == 0) {
    feat[b * 384 + col]       = com;
    feat[b * 384 + 128 + col] = var;
    feat[b * 384 + 256 + col] = skw;
  }
}

__global__ __launch_bounds__(256)
void k_pdist(const float* __restrict__ r, const float* __restrict__ sq,
             double* pd_sum, double* pd_sumsq, unsigned* pd_min, unsigned* pd_max)
{
  int ta = blockIdx.x, tb = blockIdx.y;
  if (ta > tb) return;
  __shared__ __align__(16) float pa_s[64 * DIM];
  __shared__ __align__(16) float pb_s[64 * DIM];
  __shared__ float sqa_s[64], sqb_s[64];
  const int tid = threadIdx.x;
  const int tx = tid & 15, ty = tid >> 4;

  #pragma unroll
  for (int p = 0; p < 8; ++p) {
    int q = tid + p * 256;
    int row = q >> 5, slot = q & 31;
    int pidx = ta * 64 + row;
    float4 val = make_float4(0.f, 0.f, 0.f, 0.f);
    if (pidx < NPTS) {
      int srow = pidx < 1024 ? pidx : (NPART + pidx - 1024);
      val = *(const float4*)&r[(size_t)srow * DIM + slot * 4];
    }
    *(float4*)&pa_s[lds_off(row, slot)] = val;
    pidx = tb * 64 + row;
    val = make_float4(0.f, 0.f, 0.f, 0.f);
    if (pidx < NPTS) {
      int srow = pidx < 1024 ? pidx : (NPART + pidx - 1024);
      val = *(const float4*)&r[(size_t)srow * DIM + slot * 4];
    }
    *(float4*)&pb_s[lds_off(row, slot)] = val;
  }
  if (tid < 64) {
    int pidx = ta * 64 + tid;
    sqa_s[tid] = pidx < NPTS ? sq[pidx < 1024 ? pidx : NPART + pidx - 1024] : 0.f;
  } else if (tid < 128) {
    int t2 = tid - 64;
    int pidx = tb * 64 + t2;
    sqb_s[t2] = pidx < NPTS ? sq[pidx < 1024 ? pidx : NPART + pidx - 1024] : 0.f;
  }
  __syncthreads();

  const int swi = ty & 7, swj = tx & 7;
  float sv[4][4] = {};
  #pragma unroll 8
  for (int ks = 0; ks < 32; ++ks) {
    int oi = (ks ^ swi) << 2, oj = (ks ^ swj) << 2;
    float4 av[4], bv[4];
    #pragma unroll
    for (int a = 0; a < 4; ++a) av[a] = *(const float4*)&pa_s[(ty * 4 + a) * DIM + oi];
    #pragma unroll
    for (int b = 0; b < 4; ++b) bv[b] = *(const float4*)&pb_s[(tx * 4 + b) * DIM + oj];
    #pragma unroll
    for (int a = 0; a < 4; ++a)
      #pragma unroll
      for (int b = 0; b < 4; ++b) sv[a][b] = dot4acc(sv[a][b], av[a], bv[b]);
  }

  double tsum = 0.0, tsq = 0.0;
  float tmn = 3.402823466e38f, tmx = 0.f;
  #pragma unroll
  for (int a = 0; a < 4; ++a)
    #pragma unroll
    for (int b = 0; b < 4; ++b) {
      int ga = ta * 64 + ty * 4 + a;
      int gb = tb * 64 + tx * 4 + b;
      float d2 = sqa_s[ty * 4 + a] + sqb_s[tx * 4 + b] - 2.f * sv[a][b];
      float dist = sqrtf(fmaxf(d2, 0.f));
      bool ok = (ga < NPTS) && (gb < NPTS) && ((ta != tb) || (ga < gb));
      if (ok) {
        tsum += (double)dist;
        tsq  += (double)dist * (double)dist;
        tmn = fminf(tmn, dist);
        tmx = fmaxf(tmx, dist);
      }
    }
  for (int mk = 1; mk < 64; mk <<= 1) {
    tsum += __shfl_xor(tsum, mk);
    tsq  += __shfl_xor(tsq, mk);
    tmn = fminf(tmn, __shfl_xor(tmn, mk));
    tmx = fmaxf(tmx, __shfl_xor(tmx, mk));
  }
  if ((tid & 63) == 0) {
    atomicAdd(pd_sum, tsum);
    atomicAdd(pd_sumsq, tsq);
    atomicMin(pd_min, __float_as_uint(tmn));
    atomicMax(pd_max, __float_as_uint(tmx));
  }
}

__global__ void k_proj(const float* __restrict__ feat,
                       const double* pd_sum, const double* pd_sumsq,
                       const unsigned* pd_min, const unsigned* pd_max,
                       const float* __restrict__ fw, const float* __restrict__ fb,
                       float* __restrict__ out)
{
  int t = threadIdx.x;
  int b = t >> 7, d = t & 127;
  double sm = *pd_sum, s2 = *pd_sumsq;
  double mean = sm / NPAIRS;
  double var = (s2 - sm * sm / NPAIRS) / (NPAIRS - 1.0);
  float sd = (float)sqrt(var > 0.0 ? var : 0.0);
  float mn = __uint_as_float(*pd_min);
  float mx = __uint_as_float(*pd_max);
  float acc = fb[d];
  for (int f = 0; f < 384; ++f) acc = fmaf(feat[b * 384 + f], fw[f * 128 + d], acc);
  acc = fmaf((float)mean, fw[384 * 128 + d], acc);
  acc = fmaf(sd,          fw[385 * 128 + d], acc);
  acc = fmaf(mn,          fw[386 * 128 + d], acc);
  acc = fmaf(mx,          fw[387 * 128 + d], acc);
  out[b * 128 + d] = acc;
}

extern "C" void kernel_launch(void* const* d_in, const int* in_sizes, int n_in,
                              void* d_out, int out_size, void* d_ws, size_t ws_size,
                              hipStream_t stream) {
  (void)in_sizes; (void)n_in; (void)out_size; (void)ws_size;
  const float* x   = (const float*)d_in[0];
  const float* ap  = (const float*)d_in[1];
  const float* am  = (const float*)d_in[2];
  const float* v0  = (const float*)d_in[3];
  const float* pw1 = (const float*)d_in[4];
  const float* pb1 = (const float*)d_in[5];
  const float* pw2 = (const float*)d_in[6];
  const float* kw1 = (const float*)d_in[8];
  const float* kb1 = (const float*)d_in[9];
  const float* kw2 = (const float*)d_in[10];
  const float* bw1 = (const float*)d_in[12];
  const float* bb1 = (const float*)d_in[13];
  const float* bw2 = (const float*)d_in[14];
  const float* bb2 = (const float*)d_in[15];
  const float* bw3 = (const float*)d_in[16];
  const float* bb3 = (const float*)d_in[17];
  const float* fw  = (const float*)d_in[18];
  const float* fb  = (const float*)d_in[19];

  // workspace layout (bytes), 16B-aligned; extent 21,421,856 < round-0's proven 21.47 MB
  char* ws = (char*)d_ws;
  double*   pd_sum   = (double*)(ws + 0);
  double*   pd_sumsq = (double*)(ws + 8);
  unsigned* pd_min   = (unsigned*)(ws + 16);
  unsigned* pd_max   = (unsigned*)(ws + 20);
  float*    feat     = (float*)(ws + 32);        // 4*384 f32 -> ends 6176
  float*    r        = (float*)(ws + 6176);      // MP*128 f32 -> ends 2168864
  float*    v        = (float*)(ws + 2168864);   // MP*128 f32 -> ends 4331552
  float*    sq       = (float*)(ws + 4331552);   // MP f32 -> ends 4348448
  float*    wsump    = (float*)(ws + 4348448);   // NSLICE*NROW f32 -> ends 4480800
  float*    apart    = (float*)(ws + 4480800);   // NSLICE*NROW*128 f32 -> ends 21421856

  k_init<<<MP / 4, 256, 0, stream>>>(x, ap, am, v0, r, v, sq);
  for (int it = 0; it < NITER; ++it) {
    k_force<<<dim3(NIB, NSLICE), 256, 0, stream>>>(r, sq, am, apart, wsump);
    k_rowops<<<NROW / 4, 256, 0, stream>>>(r, v, sq, apart, wsump,
        bw1, bb1, bw2, bb2, bw3, bb3, pw1, pb1, pw2, kw1, kb1, kw2,
        (it % 5) == 0 ? 1 : 0);
  }
  k_statinit<<<1, 64, 0, stream>>>(pd_sum, pd_sumsq, pd_min, pd_max);
  k_com<<<dim3(4, 4), 256, 0, stream>>>(r, am, feat);
  k_pdist<<<dim3(17, 17), 256, 0, stream>>>(r, sq, pd_sum, pd_sumsq, pd_min, pd_max);
  k_proj<<<1, 512, 0, stream>>>(feat, pd_sum, pd_sumsq, pd_min, pd_max, fw, fb,
                                (float*)d_out);
}